// Round 16
// baseline (134.197 us; speedup 1.0000x reference)
//
#include <hip/hip_runtime.h>
#include <cstddef>
#include <cstdint>

#define DMODEL 512
#define DINNER 1024
#define DSTATE 16
#define DTRANK 32
#define NB     4
#define NL     1024
#define NR     (NB * NL)   // 4096 rows (b*L)
#define CH     32
#define NCHUNK (NL / CH)   // 32
#define LOG2E  1.4426950408889634f
#define LN2    0.6931471805599453f

typedef __attribute__((ext_vector_type(8))) short bf16x8;   // 8 bf16 in 4 VGPRs
typedef __attribute__((ext_vector_type(4))) float f32x4;

__device__ __forceinline__ unsigned short f2bf(float f) {
    unsigned u = __builtin_bit_cast(unsigned, f);
    unsigned r = u + 0x7FFFu + ((u >> 16) & 1u);   // RNE
    return (unsigned short)(r >> 16);
}
__device__ __forceinline__ float bf2f(unsigned short h) {
    return __builtin_bit_cast(float, (unsigned)h << 16);
}

__device__ __forceinline__ void gload_lds16(const unsigned short* g, unsigned short* lds) {
    __builtin_amdgcn_global_load_lds(
        (const __attribute__((address_space(1))) void*)g,
        (__attribute__((address_space(3))) void*)lds, 16, 0, 0);
}

// delta = softplus(dbc_row[0:32] . wv + bias), fast softplus
__device__ __forceinline__ float delta_of_row(const float* rowp, const float4* wv, float bias) {
    const float4* db4 = (const float4*)rowp;
    float sum = bias;
#pragma unroll
    for (int q = 0; q < 8; ++q) {
        const float4 dv = db4[q];
        const float4 w = wv[q];
        sum += dv.x * w.x + dv.y * w.y + dv.z * w.z + dv.w * w.w;
    }
    const float u = __builtin_amdgcn_exp2f(-fabsf(sum) * LOG2E);
    return fmaxf(sum, 0.f) + __builtin_amdgcn_logf(1.f + u) * LN2;
}

// ---------------------------------------------------------------------------
// One-shot fp32 -> bf16 cast of all four operands + dbc zero-fill.
// ---------------------------------------------------------------------------
__global__ __launch_bounds__(256) void cast_all_kernel(
    const float* __restrict__ x, const float* __restrict__ w_in,
    const float* __restrict__ w_out, const float* __restrict__ w_xp,
    unsigned short* __restrict__ xh, unsigned short* __restrict__ wih,
    unsigned short* __restrict__ woh, unsigned short* __restrict__ xpwh,
    float* __restrict__ dbc)
{
    int i = blockIdx.x * 256 + threadIdx.x;
    if (i >= 933888) {            // dbc zero segment
        i -= 933888;
        if (i < 65536) {
            const float4 z = {0.f, 0.f, 0.f, 0.f};
            ((float4*)dbc)[i] = z;
        }
        return;
    }
    const float* src; unsigned short* dst;
    if (i < 524288)       { src = x;     dst = xh;   }
    else if (i < 786432)  { src = w_in;  dst = wih;  i -= 524288; }
    else if (i < 917504)  { src = w_out; dst = woh;  i -= 786432; }
    else                  { src = w_xp;  dst = xpwh; i -= 917504; }
    float4 v = ((const float4*)src)[i];
    ushort4 o;
    o.x = f2bf(v.x); o.y = f2bf(v.y); o.z = f2bf(v.z); o.w = f2bf(v.w);
    ((ushort4*)dst)[i] = o;
}

// ---------------------------------------------------------------------------
// bf16 MFMA GEMM: C[M,N] = A[M,K] * Bw[N,K]^T; out fp32 or bf16 (OUTBF).
// BM=128, BK=64, 256 threads (4 waves, 2x2 or 2x1 col split per BN).
// ---------------------------------------------------------------------------
template<int BN, int OUTBF>
__global__ __launch_bounds__(256) void gemm_bf16_kernel(
    const unsigned short* __restrict__ A, const unsigned short* __restrict__ Bw,
    void* __restrict__ Cv, int M, int N, int K)
{
    constexpr int BK = 64;
    constexpr int NFRAG = BN / 32;
    constexpr int BINSTR = BN / 32;
    __shared__ unsigned short As[128 * BK];
    __shared__ unsigned short Bs[BN * BK];

    const int tid  = threadIdx.x;
    const int lane = tid & 63;
    const int w    = tid >> 6;
    const int wm   = w >> 1, wn = w & 1;
    const int brow = blockIdx.y * 128;
    const int bcol = blockIdx.x * BN;

    const int srcslot = (lane & 7) ^ (lane >> 3);
    const unsigned short* ag[4];
    unsigned short* al[4];
#pragma unroll
    for (int i = 0; i < 4; ++i) {
        const int r = w * 32 + i * 8 + (lane >> 3);
        ag[i] = A + (size_t)(brow + r) * K + srcslot * 8;
        al[i] = As + (w * 32 + i * 8) * BK;
    }
    const unsigned short* bg[BINSTR];
    unsigned short* bl[BINSTR];
#pragma unroll
    for (int i = 0; i < BINSTR; ++i) {
        const int r = w * 8 * BINSTR + i * 8 + (lane >> 3);
        bg[i] = Bw + (size_t)(bcol + r) * K + srcslot * 8;
        bl[i] = Bs + (w * 8 * BINSTR + i * 8) * BK;
    }

    const int fr = lane & 15;
    const int fq = lane >> 4;
    f32x4 acc[4][NFRAG] = {};

    for (int k0 = 0; k0 < K; k0 += BK) {
#pragma unroll
        for (int i = 0; i < 4; ++i) gload_lds16(ag[i] + k0, al[i]);
#pragma unroll
        for (int i = 0; i < BINSTR; ++i) gload_lds16(bg[i] + k0, bl[i]);
        __syncthreads();
#pragma unroll
        for (int ks = 0; ks < 2; ++ks) {
            bf16x8 af[4], bfr[NFRAG];
#pragma unroll
            for (int m = 0; m < 4; ++m) {
                const int r = wm * 64 + m * 16 + fr;
                const int s = (ks * 4 + fq) ^ (r & 7);
                af[m] = *(const bf16x8*)(As + r * BK + s * 8);
            }
#pragma unroll
            for (int n = 0; n < NFRAG; ++n) {
                const int r = wn * (BN / 2) + n * 16 + fr;
                const int s = (ks * 4 + fq) ^ (r & 7);
                bfr[n] = *(const bf16x8*)(Bs + r * BK + s * 8);
            }
#pragma unroll
            for (int m = 0; m < 4; ++m)
#pragma unroll
                for (int n = 0; n < NFRAG; ++n)
                    acc[m][n] = __builtin_amdgcn_mfma_f32_16x16x32_bf16(
                        af[m], bfr[n], acc[m][n], 0, 0, 0);
        }
        __syncthreads();
    }

    const int row0 = brow + wm * 64;
    const int col0 = bcol + wn * (BN / 2);
#pragma unroll
    for (int m = 0; m < 4; ++m)
#pragma unroll
        for (int n = 0; n < NFRAG; ++n)
#pragma unroll
            for (int j = 0; j < 4; ++j) {
                const size_t ci = (size_t)(row0 + m * 16 + fq * 4 + j) * N + col0 + n * 16 + fr;
                if (OUTBF) ((unsigned short*)Cv)[ci] = f2bf(acc[m][n][j]);
                else       ((float*)Cv)[ci] = acc[m][n][j];
            }
}

// ---------------------------------------------------------------------------
// xproj split-K: dbc += xch[128-tile, Kchunk] @ xpwh[64, Kchunk]^T
// grid (NR/128, KS). Atomic fp32 epilogue (dbc pre-zeroed by cast kernel).
// ---------------------------------------------------------------------------
#define KS 4
__global__ __launch_bounds__(256) void xproj_splitk_kernel(
    const unsigned short* __restrict__ A, const unsigned short* __restrict__ Bw,
    float* __restrict__ dbc, int K)
{
    constexpr int BK = 64;
    __shared__ unsigned short As[128 * BK];
    __shared__ unsigned short Bs[64 * BK];

    const int tid  = threadIdx.x;
    const int lane = tid & 63;
    const int w    = tid >> 6;
    const int wm   = w >> 1, wn = w & 1;
    const int brow = blockIdx.x * 128;
    const int kbase = blockIdx.y * (K / KS);

    const int srcslot = (lane & 7) ^ (lane >> 3);
    const unsigned short* ag[4];
    unsigned short* al[4];
#pragma unroll
    for (int i = 0; i < 4; ++i) {
        const int r = w * 32 + i * 8 + (lane >> 3);
        ag[i] = A + (size_t)(brow + r) * K + kbase + srcslot * 8;
        al[i] = As + (w * 32 + i * 8) * BK;
    }
    const unsigned short* bg[2];
    unsigned short* bl[2];
#pragma unroll
    for (int i = 0; i < 2; ++i) {
        const int r = w * 16 + i * 8 + (lane >> 3);
        bg[i] = Bw + (size_t)r * K + kbase + srcslot * 8;
        bl[i] = Bs + (w * 16 + i * 8) * BK;
    }

    const int fr = lane & 15;
    const int fq = lane >> 4;
    f32x4 acc[4][2] = {};

    for (int k0 = 0; k0 < K / KS; k0 += BK) {
#pragma unroll
        for (int i = 0; i < 4; ++i) gload_lds16(ag[i] + k0, al[i]);
#pragma unroll
        for (int i = 0; i < 2; ++i) gload_lds16(bg[i] + k0, bl[i]);
        __syncthreads();
#pragma unroll
        for (int ks = 0; ks < 2; ++ks) {
            bf16x8 af[4], bfr[2];
#pragma unroll
            for (int m = 0; m < 4; ++m) {
                const int r = wm * 64 + m * 16 + fr;
                const int s = (ks * 4 + fq) ^ (r & 7);
                af[m] = *(const bf16x8*)(As + r * BK + s * 8);
            }
#pragma unroll
            for (int n = 0; n < 2; ++n) {
                const int r = wn * 32 + n * 16 + fr;
                const int s = (ks * 4 + fq) ^ (r & 7);
                bfr[n] = *(const bf16x8*)(Bs + r * BK + s * 8);
            }
#pragma unroll
            for (int m = 0; m < 4; ++m)
#pragma unroll
                for (int n = 0; n < 2; ++n)
                    acc[m][n] = __builtin_amdgcn_mfma_f32_16x16x32_bf16(
                        af[m], bfr[n], acc[m][n], 0, 0, 0);
        }
        __syncthreads();
    }

    const int row0 = brow + wm * 64;
    const int col0 = wn * 32;
#pragma unroll
    for (int m = 0; m < 4; ++m)
#pragma unroll
        for (int n = 0; n < 2; ++n)
#pragma unroll
            for (int j = 0; j < 4; ++j)
                unsafeAtomicAdd(
                    &dbc[(size_t)(row0 + m * 16 + fq * 4 + j) * 64 + col0 + n * 16 + fr],
                    acc[m][n][j]);
}

// ---------------------------------------------------------------------------
// Depthwise causal conv (4 taps) + SiLU, x4 vectorized, bf16 in / bf16 out.
// ---------------------------------------------------------------------------
__global__ __launch_bounds__(256) void conv_silu_kernel(
    const unsigned short* __restrict__ xzh, const float* __restrict__ conv_w,
    const float* __restrict__ conv_b, unsigned short* __restrict__ xch)
{
    const int idx4 = blockIdx.x * 256 + threadIdx.x;   // r*256 + e4
    const int e4 = idx4 & (DINNER / 4 - 1);
    const int r  = idx4 >> 8;
    const int l  = r & (NL - 1);
    const float4 cb = ((const float4*)conv_b)[e4];
    float4 w[4];
#pragma unroll
    for (int c = 0; c < 4; ++c) w[c] = ((const float4*)conv_w)[e4 * 4 + c];
    const ushort4 uz = {0, 0, 0, 0};   // bf16 zero
    const ushort4 u0 = (l >= 3) ? ((const ushort4*)(xzh + (size_t)(r - 3) * 2 * DINNER))[e4] : uz;
    const ushort4 u1 = (l >= 2) ? ((const ushort4*)(xzh + (size_t)(r - 2) * 2 * DINNER))[e4] : uz;
    const ushort4 u2 = (l >= 1) ? ((const ushort4*)(xzh + (size_t)(r - 1) * 2 * DINNER))[e4] : uz;
    const ushort4 u3 = ((const ushort4*)(xzh + (size_t)r * 2 * DINNER))[e4];
    float4 o;
    o.x = cb.x + w[0].x * bf2f(u0.x) + w[0].y * bf2f(u1.x) + w[0].z * bf2f(u2.x) + w[0].w * bf2f(u3.x);
    o.y = cb.y + w[1].x * bf2f(u0.y) + w[1].y * bf2f(u1.y) + w[1].z * bf2f(u2.y) + w[1].w * bf2f(u3.y);
    o.z = cb.z + w[2].x * bf2f(u0.z) + w[2].y * bf2f(u1.z) + w[2].z * bf2f(u2.z) + w[2].w * bf2f(u3.z);
    o.w = cb.w + w[3].x * bf2f(u0.w) + w[3].y * bf2f(u1.w) + w[3].z * bf2f(u2.w) + w[3].w * bf2f(u3.w);
    float4 s;
    s.x = o.x * __builtin_amdgcn_rcpf(1.f + __builtin_amdgcn_exp2f(-o.x * LOG2E));
    s.y = o.y * __builtin_amdgcn_rcpf(1.f + __builtin_amdgcn_exp2f(-o.y * LOG2E));
    s.z = o.z * __builtin_amdgcn_rcpf(1.f + __builtin_amdgcn_exp2f(-o.z * LOG2E));
    s.w = o.w * __builtin_amdgcn_rcpf(1.f + __builtin_amdgcn_exp2f(-o.w * LOG2E));
    ushort4 h4;
    h4.x = f2bf(s.x); h4.y = f2bf(s.y); h4.z = f2bf(s.z); h4.w = f2bf(s.w);
    ((ushort4*)xch)[idx4] = h4;
}

// ---------------------------------------------------------------------------
// Scan phase A + fused delta: compute dl inline from dbc+dtw, use it, and
// store it to yb for scanC. 16 states in registers.
// ---------------------------------------------------------------------------
__global__ __launch_bounds__(256) void scanA_kernel(
    const unsigned short* __restrict__ xch, const float* __restrict__ dbc,
    const float* __restrict__ dtw, const float* __restrict__ dtb,
    const float* __restrict__ A_log,
    float* __restrict__ chunkP, float* __restrict__ chunkS,
    float* __restrict__ yb /* delta out */)
{
    const int tid = threadIdx.x;
    const int e = blockIdx.x * 256 + tid;
    const int b = blockIdx.y, ck = blockIdx.z;
    const int rbase = b * NL + ck * CH;

    float4 wv[8];
    const float4* dtw4 = (const float4*)(dtw + (size_t)e * DTRANK);
#pragma unroll
    for (int q = 0; q < 8; ++q) wv[q] = dtw4[q];
    const float bias = dtb[e];

    float Aes2[DSTATE];
    const float4* al4 = (const float4*)(A_log + (size_t)e * DSTATE);
#pragma unroll
    for (int q = 0; q < 4; ++q) {
        const float4 a = al4[q];
        Aes2[q * 4 + 0] = -__expf(a.x) * LOG2E;
        Aes2[q * 4 + 1] = -__expf(a.y) * LOG2E;
        Aes2[q * 4 + 2] = -__expf(a.z) * LOG2E;
        Aes2[q * 4 + 3] = -__expf(a.w) * LOG2E;
    }

    float S[DSTATE];
#pragma unroll
    for (int s = 0; s < DSTATE; ++s) S[s] = 0.f;
    float cum = 0.f;
    const unsigned short* xp = xch + (size_t)rbase * DINNER + e;
    float* yp = yb + (size_t)rbase * DINNER + e;
    for (int l = 0; l < CH; ++l) {
        const float* rowp = dbc + (size_t)(rbase + l) * 64;       // wave-uniform
        const float dl = delta_of_row(rowp, wv, bias);
        yp[(size_t)l * DINNER] = dl;                               // store for scanC
        const float xv = bf2f(xp[(size_t)l * DINNER]);
        const float* bu = rowp + DTRANK;
        cum += dl;
        const float common = dl * xv;
#pragma unroll
        for (int s = 0; s < DSTATE; ++s) {
            const float dA = __builtin_amdgcn_exp2f(dl * Aes2[s]);
            S[s] = fmaf(dA, S[s], common * bu[s]);
        }
    }
    const size_t oi = (((size_t)b * NCHUNK + ck) * DINNER + e) * DSTATE;
    float4* Pp = (float4*)(chunkP + oi);
    float4* Sp = (float4*)(chunkS + oi);
#pragma unroll
    for (int q = 0; q < 4; ++q) {
        float4 pv, sv;
        pv.x = __builtin_amdgcn_exp2f(cum * Aes2[q * 4 + 0]);
        pv.y = __builtin_amdgcn_exp2f(cum * Aes2[q * 4 + 1]);
        pv.z = __builtin_amdgcn_exp2f(cum * Aes2[q * 4 + 2]);
        pv.w = __builtin_amdgcn_exp2f(cum * Aes2[q * 4 + 3]);
        sv.x = S[q * 4 + 0]; sv.y = S[q * 4 + 1];
        sv.z = S[q * 4 + 2]; sv.w = S[q * 4 + 3];
        Pp[q] = pv; Sp[q] = sv;
    }
}

// ---------------------------------------------------------------------------
// Phase B: streaming serial scan over NCHUNK summaries per (b,e,s).
// ---------------------------------------------------------------------------
__global__ __launch_bounds__(256) void scanB_kernel(
    const float* __restrict__ chunkP, float* __restrict__ chunkS)
{
    const int idx = blockIdx.x * 256 + threadIdx.x;    // 65536 threads
    const int b = idx >> 14;
    const int rem = idx & (DINNER * DSTATE - 1);
    const size_t base = (size_t)b * NCHUNK * (DINNER * DSTATE) + rem;
    float h = 0.f;
#pragma unroll 8
    for (int c = 0; c < NCHUNK; ++c) {
        const size_t i = base + (size_t)c * (DINNER * DSTATE);
        const float P = chunkP[i];
        const float S = chunkS[i];
        chunkS[i] = h;                       // h at chunk start
        h = fmaf(P, h, S);
    }
}

// ---------------------------------------------------------------------------
// Phase C: lane-per-channel re-scan from h_init; gated y written as bf16.
// ---------------------------------------------------------------------------
__global__ __launch_bounds__(256) void scanC_kernel(
    const unsigned short* __restrict__ xzh, const unsigned short* __restrict__ xch,
    const float* __restrict__ dbc, const float* __restrict__ A_log,
    const float* __restrict__ Dp, const float* __restrict__ hinit,
    const float* __restrict__ delta, unsigned short* __restrict__ yh)
{
    const int tid = threadIdx.x;
    const int e = blockIdx.x * 256 + tid;
    const int b = blockIdx.y, ck = blockIdx.z;
    const int rbase = b * NL + ck * CH;

    float Aes2[DSTATE];
    const float4* al4 = (const float4*)(A_log + (size_t)e * DSTATE);
#pragma unroll
    for (int q = 0; q < 4; ++q) {
        const float4 a = al4[q];
        Aes2[q * 4 + 0] = -__expf(a.x) * LOG2E;
        Aes2[q * 4 + 1] = -__expf(a.y) * LOG2E;
        Aes2[q * 4 + 2] = -__expf(a.z) * LOG2E;
        Aes2[q * 4 + 3] = -__expf(a.w) * LOG2E;
    }

    float h[DSTATE];
    const size_t oi = (((size_t)b * NCHUNK + ck) * DINNER + e) * DSTATE;
    const float4* h4 = (const float4*)(hinit + oi);
#pragma unroll
    for (int q = 0; q < 4; ++q) {
        const float4 v = h4[q];
        h[q * 4 + 0] = v.x; h[q * 4 + 1] = v.y; h[q * 4 + 2] = v.z; h[q * 4 + 3] = v.w;
    }
    const float Dv = Dp[e];

    const float* dp = delta + (size_t)rbase * DINNER + e;
    const unsigned short* xp = xch + (size_t)rbase * DINNER + e;
    const unsigned short* zp = xzh + (size_t)rbase * (2 * DINNER) + DINNER + e;
    unsigned short* yp = yh + (size_t)rbase * DINNER + e;

    for (int l = 0; l < CH; ++l) {
        const float dl = dp[(size_t)l * DINNER];
        const float xv = bf2f(xp[(size_t)l * DINNER]);
        const float zv = bf2f(zp[(size_t)l * 2 * DINNER]);
        const float* bu = dbc + (size_t)(rbase + l) * 64 + DTRANK;  // wave-uniform
        const float common = dl * xv;
        float y = 0.f;
#pragma unroll
        for (int s = 0; s < DSTATE; ++s) {
            const float dA = __builtin_amdgcn_exp2f(dl * Aes2[s]);
            h[s] = fmaf(dA, h[s], common * bu[s]);
            y = fmaf(h[s], bu[DSTATE + s], y);
        }
        y = fmaf(Dv, xv, y);
        const float sig = __builtin_amdgcn_rcpf(1.f + __builtin_amdgcn_exp2f(-zv * LOG2E));
        yp[(size_t)l * DINNER] = f2bf(y * (zv * sig));
    }
}

// ---------------------------------------------------------------------------
extern "C" void kernel_launch(void* const* d_in, const int* in_sizes, int n_in,
                              void* d_out, int out_size, void* d_ws, size_t ws_size,
                              hipStream_t stream)
{
    const float* x          = (const float*)d_in[0];
    const float* in_proj_w  = (const float*)d_in[1];
    const float* conv_w     = (const float*)d_in[2];
    const float* conv_b     = (const float*)d_in[3];
    const float* x_proj_w   = (const float*)d_in[4];
    const float* dt_proj_w  = (const float*)d_in[5];
    const float* dt_proj_b  = (const float*)d_in[6];
    const float* A_log      = (const float*)d_in[7];
    const float* Dp         = (const float*)d_in[8];
    const float* out_proj_w = (const float*)d_in[9];
    float* out = (float*)d_out;

    // ---- workspace layout (no aliasing; ~76 MB total) ----
    float* ws     = (float*)d_ws;
    float* dbc    = ws;                                  //   262,144 f
    float* yb     = dbc + (size_t)NR * 64;               // 4,194,304 f (delta)
    float* chunkS = yb + (size_t)NR * DINNER;            // 2,097,152 f
    float* chunkP = chunkS + (size_t)NB * NCHUNK * DINNER * DSTATE;  // 2,097,152 f
    unsigned short* xzh  = (unsigned short*)(chunkP + (size_t)NB * NCHUNK * DINNER * DSTATE);
    unsigned short* xch  = xzh + (size_t)NR * 2 * DINNER;   // 4,194,304 ush
    unsigned short* yh   = xch + (size_t)NR * DINNER;       // 4,194,304 ush
    unsigned short* xh   = yh + (size_t)NR * DINNER;        // 2,097,152 ush
    unsigned short* wih  = xh + (size_t)NR * DMODEL;        // 1,048,576 ush
    unsigned short* woh  = wih + (size_t)2 * DINNER * DMODEL;
    unsigned short* xpwh = woh + (size_t)DMODEL * DINNER;

    // 0) casts to bf16 + dbc zero-fill (one kernel)
    cast_all_kernel<<<(999424 + 255) / 256, 256, 0, stream>>>(
        x, in_proj_w, out_proj_w, x_proj_w, xh, wih, woh, xpwh, dbc);

    // 1) xz = x @ in_proj_w^T  (bf16 MFMA, bf16 out)
    gemm_bf16_kernel<128, 1><<<dim3(2 * DINNER / 128, NR / 128), 256, 0, stream>>>(
        xh, wih, xzh, NR, 2 * DINNER, DMODEL);
    // 2) causal depthwise conv + SiLU (bf16 in/out), x4 vectorized
    conv_silu_kernel<<<NR * DINNER / 1024, 256, 0, stream>>>(xzh, conv_w, conv_b, xch);
    // 3) dbc += xch @ x_proj_w^T  (split-K, 128 blocks, atomic fp32)
    xproj_splitk_kernel<<<dim3(NR / 128, KS), 256, 0, stream>>>(
        xch, xpwh, dbc, DINNER);
    // 4) scanA with fused delta (writes yb for scanC)
    scanA_kernel<<<dim3(DINNER / 256, NB, NCHUNK), 256, 0, stream>>>(
        xch, dbc, dt_proj_w, dt_proj_b, A_log, chunkP, chunkS, yb);
    scanB_kernel<<<NB * DINNER * DSTATE / 256, 256, 0, stream>>>(chunkP, chunkS);
    scanC_kernel<<<dim3(DINNER / 256, NB, NCHUNK), 256, 0, stream>>>(
        xzh, xch, dbc, A_log, Dp, chunkS, yb, yh);
    // 5) out = y @ out_proj_w^T  (bf16 MFMA, fp32 out, 512 blocks via BN=32)
    gemm_bf16_kernel<32, 0><<<dim3(DMODEL / 32, NR / 128), 256, 0, stream>>>(
        yh, woh, out, NR, DMODEL, DINNER);
}

// Round 17
// 126.038 us; speedup vs baseline: 1.0647x; 1.0647x over previous
//
#include <hip/hip_runtime.h>
#include <cstddef>
#include <cstdint>

#define DMODEL 512
#define DINNER 1024
#define DSTATE 16
#define DTRANK 32
#define NB     4
#define NL     1024
#define NR     (NB * NL)   // 4096 rows (b*L)
#define CH     32
#define NCHUNK (NL / CH)   // 32
#define LOG2E  1.4426950408889634f
#define LN2    0.6931471805599453f

typedef __attribute__((ext_vector_type(8))) short bf16x8;   // 8 bf16 in 4 VGPRs
typedef __attribute__((ext_vector_type(4))) float f32x4;

__device__ __forceinline__ unsigned short f2bf(float f) {
    unsigned u = __builtin_bit_cast(unsigned, f);
    unsigned r = u + 0x7FFFu + ((u >> 16) & 1u);   // RNE
    return (unsigned short)(r >> 16);
}
__device__ __forceinline__ float bf2f(unsigned short h) {
    return __builtin_bit_cast(float, (unsigned)h << 16);
}

__device__ __forceinline__ void gload_lds16(const unsigned short* g, unsigned short* lds) {
    __builtin_amdgcn_global_load_lds(
        (const __attribute__((address_space(1))) void*)g,
        (__attribute__((address_space(3))) void*)lds, 16, 0, 0);
}

// ---------------------------------------------------------------------------
// One-shot fp32 -> bf16 cast of all four operands + dbc zero-fill.
// ---------------------------------------------------------------------------
__global__ __launch_bounds__(256) void cast_all_kernel(
    const float* __restrict__ x, const float* __restrict__ w_in,
    const float* __restrict__ w_out, const float* __restrict__ w_xp,
    unsigned short* __restrict__ xh, unsigned short* __restrict__ wih,
    unsigned short* __restrict__ woh, unsigned short* __restrict__ xpwh,
    float* __restrict__ dbc)
{
    int i = blockIdx.x * 256 + threadIdx.x;
    if (i >= 933888) {            // dbc zero segment
        i -= 933888;
        if (i < 65536) {
            const float4 z = {0.f, 0.f, 0.f, 0.f};
            ((float4*)dbc)[i] = z;
        }
        return;
    }
    const float* src; unsigned short* dst;
    if (i < 524288)       { src = x;     dst = xh;   }
    else if (i < 786432)  { src = w_in;  dst = wih;  i -= 524288; }
    else if (i < 917504)  { src = w_out; dst = woh;  i -= 786432; }
    else                  { src = w_xp;  dst = xpwh; i -= 917504; }
    float4 v = ((const float4*)src)[i];
    ushort4 o;
    o.x = f2bf(v.x); o.y = f2bf(v.y); o.z = f2bf(v.z); o.w = f2bf(v.w);
    ((ushort4*)dst)[i] = o;
}

// ---------------------------------------------------------------------------
// bf16 MFMA GEMM: C[M,N] = A[M,K] * Bw[N,K]^T; out fp32 or bf16 (OUTBF).
// BM=128, BK=64, 256 threads (4 waves).
// ---------------------------------------------------------------------------
template<int BN, int OUTBF>
__global__ __launch_bounds__(256) void gemm_bf16_kernel(
    const unsigned short* __restrict__ A, const unsigned short* __restrict__ Bw,
    void* __restrict__ Cv, int M, int N, int K)
{
    constexpr int BK = 64;
    constexpr int NFRAG = BN / 32;
    constexpr int BINSTR = BN / 32;
    __shared__ unsigned short As[128 * BK];
    __shared__ unsigned short Bs[BN * BK];

    const int tid  = threadIdx.x;
    const int lane = tid & 63;
    const int w    = tid >> 6;
    const int wm   = w >> 1, wn = w & 1;
    const int brow = blockIdx.y * 128;
    const int bcol = blockIdx.x * BN;

    const int srcslot = (lane & 7) ^ (lane >> 3);
    const unsigned short* ag[4];
    unsigned short* al[4];
#pragma unroll
    for (int i = 0; i < 4; ++i) {
        const int r = w * 32 + i * 8 + (lane >> 3);
        ag[i] = A + (size_t)(brow + r) * K + srcslot * 8;
        al[i] = As + (w * 32 + i * 8) * BK;
    }
    const unsigned short* bg[BINSTR];
    unsigned short* bl[BINSTR];
#pragma unroll
    for (int i = 0; i < BINSTR; ++i) {
        const int r = w * 8 * BINSTR + i * 8 + (lane >> 3);
        bg[i] = Bw + (size_t)(bcol + r) * K + srcslot * 8;
        bl[i] = Bs + (w * 8 * BINSTR + i * 8) * BK;
    }

    const int fr = lane & 15;
    const int fq = lane >> 4;
    f32x4 acc[4][NFRAG] = {};

    for (int k0 = 0; k0 < K; k0 += BK) {
#pragma unroll
        for (int i = 0; i < 4; ++i) gload_lds16(ag[i] + k0, al[i]);
#pragma unroll
        for (int i = 0; i < BINSTR; ++i) gload_lds16(bg[i] + k0, bl[i]);
        __syncthreads();
#pragma unroll
        for (int ks = 0; ks < 2; ++ks) {
            bf16x8 af[4], bfr[NFRAG];
#pragma unroll
            for (int m = 0; m < 4; ++m) {
                const int r = wm * 64 + m * 16 + fr;
                const int s = (ks * 4 + fq) ^ (r & 7);
                af[m] = *(const bf16x8*)(As + r * BK + s * 8);
            }
#pragma unroll
            for (int n = 0; n < NFRAG; ++n) {
                const int r = wn * (BN / 2) + n * 16 + fr;
                const int s = (ks * 4 + fq) ^ (r & 7);
                bfr[n] = *(const bf16x8*)(Bs + r * BK + s * 8);
            }
#pragma unroll
            for (int m = 0; m < 4; ++m)
#pragma unroll
                for (int n = 0; n < NFRAG; ++n)
                    acc[m][n] = __builtin_amdgcn_mfma_f32_16x16x32_bf16(
                        af[m], bfr[n], acc[m][n], 0, 0, 0);
        }
        __syncthreads();
    }

    const int row0 = brow + wm * 64;
    const int col0 = bcol + wn * (BN / 2);
#pragma unroll
    for (int m = 0; m < 4; ++m)
#pragma unroll
        for (int n = 0; n < NFRAG; ++n)
#pragma unroll
            for (int j = 0; j < 4; ++j) {
                const size_t ci = (size_t)(row0 + m * 16 + fq * 4 + j) * N + col0 + n * 16 + fr;
                if (OUTBF) ((unsigned short*)Cv)[ci] = f2bf(acc[m][n][j]);
                else       ((float*)Cv)[ci] = acc[m][n][j];
            }
}

// ---------------------------------------------------------------------------
// xproj split-K: dbc += xch[128-tile, Kchunk] @ xpwh[64, Kchunk]^T
// grid (NR/128, KS). Atomic fp32 epilogue (dbc pre-zeroed by cast kernel).
// ---------------------------------------------------------------------------
#define KS 4
__global__ __launch_bounds__(256) void xproj_splitk_kernel(
    const unsigned short* __restrict__ A, const unsigned short* __restrict__ Bw,
    float* __restrict__ dbc, int K)
{
    constexpr int BK = 64;
    __shared__ unsigned short As[128 * BK];
    __shared__ unsigned short Bs[64 * BK];

    const int tid  = threadIdx.x;
    const int lane = tid & 63;
    const int w    = tid >> 6;
    const int wm   = w >> 1, wn = w & 1;
    const int brow = blockIdx.x * 128;
    const int kbase = blockIdx.y * (K / KS);

    const int srcslot = (lane & 7) ^ (lane >> 3);
    const unsigned short* ag[4];
    unsigned short* al[4];
#pragma unroll
    for (int i = 0; i < 4; ++i) {
        const int r = w * 32 + i * 8 + (lane >> 3);
        ag[i] = A + (size_t)(brow + r) * K + kbase + srcslot * 8;
        al[i] = As + (w * 32 + i * 8) * BK;
    }
    const unsigned short* bg[2];
    unsigned short* bl[2];
#pragma unroll
    for (int i = 0; i < 2; ++i) {
        const int r = w * 16 + i * 8 + (lane >> 3);
        bg[i] = Bw + (size_t)r * K + kbase + srcslot * 8;
        bl[i] = Bs + (w * 16 + i * 8) * BK;
    }

    const int fr = lane & 15;
    const int fq = lane >> 4;
    f32x4 acc[4][2] = {};

    for (int k0 = 0; k0 < K / KS; k0 += BK) {
#pragma unroll
        for (int i = 0; i < 4; ++i) gload_lds16(ag[i] + k0, al[i]);
#pragma unroll
        for (int i = 0; i < 2; ++i) gload_lds16(bg[i] + k0, bl[i]);
        __syncthreads();
#pragma unroll
        for (int ks = 0; ks < 2; ++ks) {
            bf16x8 af[4], bfr[2];
#pragma unroll
            for (int m = 0; m < 4; ++m) {
                const int r = wm * 64 + m * 16 + fr;
                const int s = (ks * 4 + fq) ^ (r & 7);
                af[m] = *(const bf16x8*)(As + r * BK + s * 8);
            }
#pragma unroll
            for (int n = 0; n < 2; ++n) {
                const int r = wn * 32 + n * 16 + fr;
                const int s = (ks * 4 + fq) ^ (r & 7);
                bfr[n] = *(const bf16x8*)(Bs + r * BK + s * 8);
            }
#pragma unroll
            for (int m = 0; m < 4; ++m)
#pragma unroll
                for (int n = 0; n < 2; ++n)
                    acc[m][n] = __builtin_amdgcn_mfma_f32_16x16x32_bf16(
                        af[m], bfr[n], acc[m][n], 0, 0, 0);
        }
        __syncthreads();
    }

    const int row0 = brow + wm * 64;
    const int col0 = wn * 32;
#pragma unroll
    for (int m = 0; m < 4; ++m)
#pragma unroll
        for (int n = 0; n < 2; ++n)
#pragma unroll
            for (int j = 0; j < 4; ++j)
                unsafeAtomicAdd(
                    &dbc[(size_t)(row0 + m * 16 + fq * 4 + j) * 64 + col0 + n * 16 + fr],
                    acc[m][n][j]);
}

// ---------------------------------------------------------------------------
// Depthwise causal conv (4 taps) + SiLU, x4 vectorized, bf16 in / bf16 out.
// ---------------------------------------------------------------------------
__global__ __launch_bounds__(256) void conv_silu_kernel(
    const unsigned short* __restrict__ xzh, const float* __restrict__ conv_w,
    const float* __restrict__ conv_b, unsigned short* __restrict__ xch)
{
    const int idx4 = blockIdx.x * 256 + threadIdx.x;   // r*256 + e4
    const int e4 = idx4 & (DINNER / 4 - 1);
    const int r  = idx4 >> 8;
    const int l  = r & (NL - 1);
    const float4 cb = ((const float4*)conv_b)[e4];
    float4 w[4];
#pragma unroll
    for (int c = 0; c < 4; ++c) w[c] = ((const float4*)conv_w)[e4 * 4 + c];
    const ushort4 uz = {0, 0, 0, 0};   // bf16 zero
    const ushort4 u0 = (l >= 3) ? ((const ushort4*)(xzh + (size_t)(r - 3) * 2 * DINNER))[e4] : uz;
    const ushort4 u1 = (l >= 2) ? ((const ushort4*)(xzh + (size_t)(r - 2) * 2 * DINNER))[e4] : uz;
    const ushort4 u2 = (l >= 1) ? ((const ushort4*)(xzh + (size_t)(r - 1) * 2 * DINNER))[e4] : uz;
    const ushort4 u3 = ((const ushort4*)(xzh + (size_t)r * 2 * DINNER))[e4];
    float4 o;
    o.x = cb.x + w[0].x * bf2f(u0.x) + w[0].y * bf2f(u1.x) + w[0].z * bf2f(u2.x) + w[0].w * bf2f(u3.x);
    o.y = cb.y + w[1].x * bf2f(u0.y) + w[1].y * bf2f(u1.y) + w[1].z * bf2f(u2.y) + w[1].w * bf2f(u3.y);
    o.z = cb.z + w[2].x * bf2f(u0.z) + w[2].y * bf2f(u1.z) + w[2].z * bf2f(u2.z) + w[2].w * bf2f(u3.z);
    o.w = cb.w + w[3].x * bf2f(u0.w) + w[3].y * bf2f(u1.w) + w[3].z * bf2f(u2.w) + w[3].w * bf2f(u3.w);
    float4 s;
    s.x = o.x * __builtin_amdgcn_rcpf(1.f + __builtin_amdgcn_exp2f(-o.x * LOG2E));
    s.y = o.y * __builtin_amdgcn_rcpf(1.f + __builtin_amdgcn_exp2f(-o.y * LOG2E));
    s.z = o.z * __builtin_amdgcn_rcpf(1.f + __builtin_amdgcn_exp2f(-o.z * LOG2E));
    s.w = o.w * __builtin_amdgcn_rcpf(1.f + __builtin_amdgcn_exp2f(-o.w * LOG2E));
    ushort4 h4;
    h4.x = f2bf(s.x); h4.y = f2bf(s.y); h4.z = f2bf(s.z); h4.w = f2bf(s.w);
    ((ushort4*)xch)[idx4] = h4;
}

// ---------------------------------------------------------------------------
// delta[r,e] = softplus(dbc[r,0:32] . dt_proj_w[e,:] + dt_proj_b[e])
// ---------------------------------------------------------------------------
#define DRT 32
__global__ __launch_bounds__(256) void delta_kernel(
    const float* __restrict__ dbc, const float* __restrict__ dtw,
    const float* __restrict__ dtb, float* __restrict__ delta)
{
    __shared__ float dlds[DRT * DTRANK];   // 4 KB
    const int t = threadIdx.x;
    const int e = blockIdx.x * 256 + t;
    const int r0 = blockIdx.y * DRT;
    for (int i = t; i < DRT * DTRANK; i += 256) {
        const int row = i >> 5, jj = i & 31;
        dlds[i] = dbc[(size_t)(r0 + row) * 64 + jj];
    }
    float4 wv[8];
    const float4* dtw4 = (const float4*)(dtw + (size_t)e * DTRANK);
#pragma unroll
    for (int q = 0; q < 8; ++q) wv[q] = dtw4[q];
    const float bias = dtb[e];
    __syncthreads();
#pragma unroll 4
    for (int row = 0; row < DRT; ++row) {
        const float4* dl4 = (const float4*)(dlds + row * DTRANK);
        float sum = bias;
#pragma unroll
        for (int q = 0; q < 8; ++q) {
            const float4 dv = dl4[q];
            const float4 w = wv[q];
            sum += dv.x * w.x + dv.y * w.y + dv.z * w.z + dv.w * w.w;
        }
        const float u = __builtin_amdgcn_exp2f(-fabsf(sum) * LOG2E);
        delta[(size_t)(r0 + row) * DINNER + e] =
            fmaxf(sum, 0.f) + __builtin_amdgcn_logf(1.f + u) * LN2;
    }
}

// ---------------------------------------------------------------------------
// Scan phase A: lane-per-channel, 16 states in registers (streaming loop).
// ---------------------------------------------------------------------------
__global__ __launch_bounds__(256) void scanA_kernel(
    const float* __restrict__ delta, const unsigned short* __restrict__ xch,
    const float* __restrict__ dbc, const float* __restrict__ A_log,
    float* __restrict__ chunkP, float* __restrict__ chunkS)
{
    const int tid = threadIdx.x;
    const int e = blockIdx.x * 256 + tid;
    const int b = blockIdx.y, ck = blockIdx.z;
    const int rbase = b * NL + ck * CH;

    float Aes2[DSTATE];
    const float4* al4 = (const float4*)(A_log + (size_t)e * DSTATE);
#pragma unroll
    for (int q = 0; q < 4; ++q) {
        const float4 a = al4[q];
        Aes2[q * 4 + 0] = -__expf(a.x) * LOG2E;
        Aes2[q * 4 + 1] = -__expf(a.y) * LOG2E;
        Aes2[q * 4 + 2] = -__expf(a.z) * LOG2E;
        Aes2[q * 4 + 3] = -__expf(a.w) * LOG2E;
    }

    float S[DSTATE];
#pragma unroll
    for (int s = 0; s < DSTATE; ++s) S[s] = 0.f;
    float cum = 0.f;
    const float* dp = delta + (size_t)rbase * DINNER + e;
    const unsigned short* xp = xch + (size_t)rbase * DINNER + e;
    for (int l = 0; l < CH; ++l) {
        const float dl = dp[(size_t)l * DINNER];
        const float xv = bf2f(xp[(size_t)l * DINNER]);
        const float* bu = dbc + (size_t)(rbase + l) * 64 + DTRANK;  // wave-uniform
        cum += dl;
        const float common = dl * xv;
#pragma unroll
        for (int s = 0; s < DSTATE; ++s) {
            const float dA = __builtin_amdgcn_exp2f(dl * Aes2[s]);
            S[s] = fmaf(dA, S[s], common * bu[s]);
        }
    }
    const size_t oi = (((size_t)b * NCHUNK + ck) * DINNER + e) * DSTATE;
    float4* Pp = (float4*)(chunkP + oi);
    float4* Sp = (float4*)(chunkS + oi);
#pragma unroll
    for (int q = 0; q < 4; ++q) {
        float4 pv, sv;
        pv.x = __builtin_amdgcn_exp2f(cum * Aes2[q * 4 + 0]);
        pv.y = __builtin_amdgcn_exp2f(cum * Aes2[q * 4 + 1]);
        pv.z = __builtin_amdgcn_exp2f(cum * Aes2[q * 4 + 2]);
        pv.w = __builtin_amdgcn_exp2f(cum * Aes2[q * 4 + 3]);
        sv.x = S[q * 4 + 0]; sv.y = S[q * 4 + 1];
        sv.z = S[q * 4 + 2]; sv.w = S[q * 4 + 3];
        Pp[q] = pv; Sp[q] = sv;
    }
}

// ---------------------------------------------------------------------------
// Phase B: streaming serial scan over NCHUNK summaries per (b,e,s).
// ---------------------------------------------------------------------------
__global__ __launch_bounds__(256) void scanB_kernel(
    const float* __restrict__ chunkP, float* __restrict__ chunkS)
{
    const int idx = blockIdx.x * 256 + threadIdx.x;    // 65536 threads
    const int b = idx >> 14;
    const int rem = idx & (DINNER * DSTATE - 1);
    const size_t base = (size_t)b * NCHUNK * (DINNER * DSTATE) + rem;
    float h = 0.f;
#pragma unroll 8
    for (int c = 0; c < NCHUNK; ++c) {
        const size_t i = base + (size_t)c * (DINNER * DSTATE);
        const float P = chunkP[i];
        const float S = chunkS[i];
        chunkS[i] = h;                       // h at chunk start
        h = fmaf(P, h, S);
    }
}

// ---------------------------------------------------------------------------
// Phase C: lane-per-channel re-scan from h_init; gated y written as bf16.
// ---------------------------------------------------------------------------
__global__ __launch_bounds__(256) void scanC_kernel(
    const unsigned short* __restrict__ xzh, const unsigned short* __restrict__ xch,
    const float* __restrict__ dbc, const float* __restrict__ A_log,
    const float* __restrict__ Dp, const float* __restrict__ hinit,
    const float* __restrict__ delta, unsigned short* __restrict__ yh)
{
    const int tid = threadIdx.x;
    const int e = blockIdx.x * 256 + tid;
    const int b = blockIdx.y, ck = blockIdx.z;
    const int rbase = b * NL + ck * CH;

    float Aes2[DSTATE];
    const float4* al4 = (const float4*)(A_log + (size_t)e * DSTATE);
#pragma unroll
    for (int q = 0; q < 4; ++q) {
        const float4 a = al4[q];
        Aes2[q * 4 + 0] = -__expf(a.x) * LOG2E;
        Aes2[q * 4 + 1] = -__expf(a.y) * LOG2E;
        Aes2[q * 4 + 2] = -__expf(a.z) * LOG2E;
        Aes2[q * 4 + 3] = -__expf(a.w) * LOG2E;
    }

    float h[DSTATE];
    const size_t oi = (((size_t)b * NCHUNK + ck) * DINNER + e) * DSTATE;
    const float4* h4 = (const float4*)(hinit + oi);
#pragma unroll
    for (int q = 0; q < 4; ++q) {
        const float4 v = h4[q];
        h[q * 4 + 0] = v.x; h[q * 4 + 1] = v.y; h[q * 4 + 2] = v.z; h[q * 4 + 3] = v.w;
    }
    const float Dv = Dp[e];

    const float* dp = delta + (size_t)rbase * DINNER + e;
    const unsigned short* xp = xch + (size_t)rbase * DINNER + e;
    const unsigned short* zp = xzh + (size_t)rbase * (2 * DINNER) + DINNER + e;
    unsigned short* yp = yh + (size_t)rbase * DINNER + e;

    for (int l = 0; l < CH; ++l) {
        const float dl = dp[(size_t)l * DINNER];
        const float xv = bf2f(xp[(size_t)l * DINNER]);
        const float zv = bf2f(zp[(size_t)l * 2 * DINNER]);
        const float* bu = dbc + (size_t)(rbase + l) * 64 + DTRANK;  // wave-uniform
        const float common = dl * xv;
        float y = 0.f;
#pragma unroll
        for (int s = 0; s < DSTATE; ++s) {
            const float dA = __builtin_amdgcn_exp2f(dl * Aes2[s]);
            h[s] = fmaf(dA, h[s], common * bu[s]);
            y = fmaf(h[s], bu[DSTATE + s], y);
        }
        y = fmaf(Dv, xv, y);
        const float sig = __builtin_amdgcn_rcpf(1.f + __builtin_amdgcn_exp2f(-zv * LOG2E));
        yp[(size_t)l * DINNER] = f2bf(y * (zv * sig));
    }
}

// ---------------------------------------------------------------------------
extern "C" void kernel_launch(void* const* d_in, const int* in_sizes, int n_in,
                              void* d_out, int out_size, void* d_ws, size_t ws_size,
                              hipStream_t stream)
{
    const float* x          = (const float*)d_in[0];
    const float* in_proj_w  = (const float*)d_in[1];
    const float* conv_w     = (const float*)d_in[2];
    const float* conv_b     = (const float*)d_in[3];
    const float* x_proj_w   = (const float*)d_in[4];
    const float* dt_proj_w  = (const float*)d_in[5];
    const float* dt_proj_b  = (const float*)d_in[6];
    const float* A_log      = (const float*)d_in[7];
    const float* Dp         = (const float*)d_in[8];
    const float* out_proj_w = (const float*)d_in[9];
    float* out = (float*)d_out;

    // ---- workspace layout (no aliasing; ~76 MB total) ----
    float* ws     = (float*)d_ws;
    float* dbc    = ws;                                  //   262,144 f
    float* yb     = dbc + (size_t)NR * 64;               // 4,194,304 f (delta)
    float* chunkS = yb + (size_t)NR * DINNER;            // 2,097,152 f
    float* chunkP = chunkS + (size_t)NB * NCHUNK * DINNER * DSTATE;  // 2,097,152 f
    unsigned short* xzh  = (unsigned short*)(chunkP + (size_t)NB * NCHUNK * DINNER * DSTATE);
    unsigned short* xch  = xzh + (size_t)NR * 2 * DINNER;   // 4,194,304 ush
    unsigned short* yh   = xch + (size_t)NR * DINNER;       // 4,194,304 ush
    unsigned short* xh   = yh + (size_t)NR * DINNER;        // 2,097,152 ush
    unsigned short* wih  = xh + (size_t)NR * DMODEL;        // 1,048,576 ush
    unsigned short* woh  = wih + (size_t)2 * DINNER * DMODEL;
    unsigned short* xpwh = woh + (size_t)DMODEL * DINNER;

    // 0) casts to bf16 + dbc zero-fill (one kernel)
    cast_all_kernel<<<(999424 + 255) / 256, 256, 0, stream>>>(
        x, in_proj_w, out_proj_w, x_proj_w, xh, wih, woh, xpwh, dbc);

    // 1) xz = x @ in_proj_w^T  (bf16 MFMA, bf16 out)
    gemm_bf16_kernel<128, 1><<<dim3(2 * DINNER / 128, NR / 128), 256, 0, stream>>>(
        xh, wih, xzh, NR, 2 * DINNER, DMODEL);
    // 2) causal depthwise conv + SiLU (bf16 in/out), x4 vectorized
    conv_silu_kernel<<<NR * DINNER / 1024, 256, 0, stream>>>(xzh, conv_w, conv_b, xch);
    // 3) dbc += xch @ x_proj_w^T  (split-K, 128 blocks, atomic fp32)
    xproj_splitk_kernel<<<dim3(NR / 128, KS), 256, 0, stream>>>(
        xch, xpwh, dbc, DINNER);
    // 4) delta = softplus(dbc[:, :32] @ dt_proj_w^T + b)
    delta_kernel<<<dim3(DINNER / 256, NR / DRT), 256, 0, stream>>>(
        dbc, dt_proj_w, dt_proj_b, yb);
    // 5) chunked parallel scan
    scanA_kernel<<<dim3(DINNER / 256, NB, NCHUNK), 256, 0, stream>>>(
        yb, xch, dbc, A_log, chunkP, chunkS);
    scanB_kernel<<<NB * DINNER * DSTATE / 256, 256, 0, stream>>>(chunkP, chunkS);
    scanC_kernel<<<dim3(DINNER / 256, NB, NCHUNK), 256, 0, stream>>>(
        xzh, xch, dbc, A_log, Dp, chunkS, yb, yh);
    // 6) out = y @ out_proj_w^T  (bf16 MFMA, fp32 out, 512 blocks via BN=32)
    gemm_bf16_kernel<32, 0><<<dim3(DMODEL / 32, NR / 128), 256, 0, stream>>>(
        yh, woh, out, NR, DMODEL, DINNER);
}